// Round 12
// baseline (1294.449 us; speedup 1.0000x reference)
//
#include <hip/hip_runtime.h>
#include <hip/hip_bf16.h>

#define HH 128
#define WW 128

typedef _Float16 half2_t __attribute__((ext_vector_type(2)));
typedef _Float16 half4_t __attribute__((ext_vector_type(4)));
typedef _Float16 half8 __attribute__((ext_vector_type(8)));
typedef float f32x4 __attribute__((ext_vector_type(4)));

// ---------------------------------------------------------------------------
// Weight transform: fp32 [oc][ic][3][3] -> f16 [tap][oc][ic] per layer.
// Layers 0..15 rb_w1, 16..31 rb_w2, 32 body (OC=64), 33 super (OC padded 448).
// Plus out-conv weights packed as f16 ic-PAIRS: Wo[(c*50+p)*9+tap] = half2.
// ---------------------------------------------------------------------------
__global__ __launch_bounds__(256)
void wxform_k(const float* __restrict__ rb_w1, const float* __restrict__ rb_w2,
              const float* __restrict__ body_w, const float* __restrict__ super_w,
              const float* __restrict__ out_w,
              _Float16* __restrict__ Wt, _Float16* __restrict__ Wo) {
    const int per64 = 64 * 64 * 9;          // 36864
    const int n64   = 33 * per64;           // 1216512
    const int nW    = n64 + 448 * 64 * 9;   // 1474560
    const int total = nW + 1350;            // + out-conv pairs
    for (int i = blockIdx.x * 256 + threadIdx.x; i < total; i += gridDim.x * 256) {
        if (i < n64) {
            int l  = i / per64;
            int r  = i - l * per64;
            int ic = r & 63, oc = (r >> 6) & 63, tap = r >> 12;
            const float* src = (l < 16) ? (rb_w1 + (size_t)l * per64)
                             : (l < 32) ? (rb_w2 + (size_t)(l - 16) * per64)
                                        : body_w;
            Wt[i] = (_Float16)src[(oc * 64 + ic) * 9 + tap];
        } else if (i < nW) {
            int r   = i - n64;
            int ic  = r & 63;
            int oc  = (r >> 6) % 448;
            int tap = (r >> 6) / 448;
            float v = (oc < 400) ? super_w[((size_t)oc * 64 + ic) * 9 + tap] : 0.f;
            Wt[i] = (_Float16)v;
        } else {
            int j = i - nW;            // 0..1349 : c(3) x p(50) x tap(9)
            int c = j / 450, r = j - c * 450;
            int p = r / 9, tap = r - p * 9;
            Wo[j * 2]     = (_Float16)out_w[(c * 100 + 2 * p) * 9 + tap];
            Wo[j * 2 + 1] = (_Float16)out_w[(c * 100 + 2 * p + 1) * 9 + tap];
        }
    }
}

// ---------------------------------------------------------------------------
// Head conv: 3 -> 64, fused mean subtraction. Output f16 4c layout.
// ---------------------------------------------------------------------------
__global__ __launch_bounds__(256)
void head_k(const float* __restrict__ x, const float* __restrict__ w,
            const float* __restrict__ b, _Float16* __restrict__ out) {
    int n  = blockIdx.z;
    int gx = blockIdx.x * 16 + (threadIdx.x & 15);
    int gy = blockIdx.y * 16 + (threadIdx.x >> 4);
    float msub[3] = {255.0f * 0.4488f, 255.0f * 0.4371f, 255.0f * 0.4040f};
    float iv[27];
#pragma unroll
    for (int c = 0; c < 3; ++c)
#pragma unroll
        for (int dy = 0; dy < 3; ++dy)
#pragma unroll
            for (int dx = 0; dx < 3; ++dx) {
                int yy = gy + dy - 1, xx = gx + dx - 1;
                float v = 0.f;
                if ((unsigned)yy < HH && (unsigned)xx < WW)
                    v = x[(((size_t)n * 3 + c) * HH + yy) * WW + xx] - msub[c];
                iv[c * 9 + dy * 3 + dx] = v;
            }
    for (int ocg = 0; ocg < 16; ++ocg) {
        half4_t o;
#pragma unroll
        for (int q = 0; q < 4; ++q) {
            int oc  = ocg * 4 + q;
            float a = b[oc];
#pragma unroll
            for (int t = 0; t < 27; ++t) a = fmaf(iv[t], w[oc * 27 + t], a);
            o[q] = (_Float16)a;
        }
        *(half4_t*)&out[((((size_t)n * 16 + ocg) * HH + gy) * WW + gx) * 4] = o;
    }
}

// ---------------------------------------------------------------------------
// Fused resblock, r12: 13x12 output tile, LDS 52 KB -> 3 blocks/CU (12
// waves/CU, was 8 -- occupancy beats per-block LDS economy, per r11-mconv).
// sIn 16x17x64 (34.8 KB, aliased by sMid). sW = one 32oc x 32ic quarter
// (9 x 16 oc-pairs x 64 f16 = 18.4 KB, xor pair-packed, <=2-way banks).
// 8 compute phases (oc-half x ic-half per conv), reg-prefetch hides global
// weight latency. conv1: 4 waves x 4 rows (rows -1..14) x chunk-32-oc.
// conv2: 4 waves x 3 rows x all-64-oc. Residual captured to regs.
// Halo overreads land in-bounds (sW region) and feed only discarded rows.
// ---------------------------------------------------------------------------
__global__ __launch_bounds__(256, 3)
void frb1_k(const _Float16* __restrict__ in, const _Float16* __restrict__ W1,
            const _Float16* __restrict__ W2, const float* __restrict__ b1,
            const float* __restrict__ b2, _Float16* __restrict__ out) {
    __shared__ __align__(16) _Float16 sBuf[17408 + 9216];  // 53248 B
    _Float16* sIn  = sBuf;          // 16 rows x 17 cols x 64
    _Float16* sMid = sBuf;          // aliased after conv1 reads done
    _Float16* sW   = sBuf + 17408;  // 9 tap x 16 oc-pairs x 64

    int tid = threadIdx.x;
    int bx = blockIdx.x, by = blockIdx.y, n = blockIdx.z;
    int wv = tid >> 6, lane = tid & 63;
    int lx = lane & 15, lg = lane >> 4;
    int o0 = wv * 4 - 1;            // conv1-out rows o0..o0+3 (covers -1..14)
    int m0 = wv * 3;                // conv2-out rows m0..m0+2

    half8 pf[5];
#define PF_W(Wsrc, icoff, ocoff)                                              \
    _Pragma("unroll")                                                         \
    for (int j = 0; j < 5; ++j) {                                             \
        int i = tid + 256 * j;                                                \
        if (i < 1152) {                                                       \
            int g = i & 3, ocl = (i >> 2) & 31, tap = i >> 7;                 \
            pf[j] = *(const half8*)&Wsrc[(size_t)(tap * 64 + (ocoff) + ocl) * 64 + (icoff) + g * 8]; \
        }                                                                     \
    }
#define WR_W()                                                                \
    _Pragma("unroll")                                                         \
    for (int j = 0; j < 5; ++j) {                                             \
        int i = tid + 256 * j;                                                \
        if (i < 1152) {                                                       \
            int g = i & 3, ocl = (i >> 2) & 31, tap = i >> 7;                 \
            *(half8*)&sW[(tap * 16 + (ocl >> 1)) * 64 +                       \
                         (((g + (ocl & 1) * 4) ^ ((ocl >> 1) & 7)) << 3)] = pf[j]; \
        }                                                                     \
    }
#define RD_A(tap, oc)                                                         \
    (*(const half8*)&sW[((tap) * 16 + ((oc) >> 1)) * 64 +                     \
                        (((lg + ((oc) & 1) * 4) ^ (((oc) >> 1) & 7)) << 3)])

    // ---- P0: prefetch W1(ic0,oc0), stage sIn, write sW ----
    PF_W(W1, 0, 0)
    for (int i = tid; i < 2176; i += 256) {     // 16 rows x 17 cols x 8 icg
        int icg = i / 272, pl = i - icg * 272;
        int py = pl / 17, px = pl - py * 17;
        int gy = by * 12 + py - 2, gx = bx * 13 + px - 2;
        half8 v = {0, 0, 0, 0, 0, 0, 0, 0};
        if ((unsigned)gy < (unsigned)HH && (unsigned)gx < (unsigned)WW) {
            size_t base = ((((size_t)n * 16 + icg * 2) * HH + gy) * WW + gx) * 4;
            half4_t a = *(const half4_t*)&in[base];
            half4_t c = *(const half4_t*)&in[base + (size_t)HH * WW * 4];
            v[0] = a[0]; v[1] = a[1]; v[2] = a[2]; v[3] = a[3];
            v[4] = c[0]; v[5] = c[1]; v[6] = c[2]; v[7] = c[3];
        }
        *(half8*)&sIn[pl * 64 + ((icg ^ (pl & 7)) << 3)] = v;
    }
    WR_W()
    __syncthreads();

    f32x4 acc1[4][4];   // [row][ochalf*2 + t]
#pragma unroll
    for (int r = 0; r < 4; ++r)
#pragma unroll
        for (int t = 0; t < 4; ++t) acc1[r][t] = (f32x4){0.f, 0.f, 0.f, 0.f};

// conv1 compute: current sW chunk = 32 oc; accumulate into slots os,os+1.
// B: rows o0+d+1 (overreads for wv3 stay in-bounds, feed discarded rows).
#define CONV1_CHUNK(ch, os)                                                   \
    {                                                                         \
        _Pragma("unroll")                                                     \
        for (int dx = 0; dx < 3; ++dx) {                                      \
            half8 Bf[6];                                                      \
            _Pragma("unroll")                                                 \
            for (int d = 0; d < 6; ++d) {                                     \
                int pl = (o0 + d + 1) * 17 + (lx + dx);                       \
                Bf[d] = *(const half8*)&sIn[pl * 64 + ((((ch) + lg) ^ (pl & 7)) << 3)]; \
            }                                                                 \
            _Pragma("unroll")                                                 \
            for (int dy = 0; dy < 3; ++dy) {                                  \
                int tap = dy * 3 + dx;                                        \
                half8 Af[2];                                                  \
                _Pragma("unroll")                                             \
                for (int t = 0; t < 2; ++t) Af[t] = RD_A(tap, t * 16 + lx);   \
                _Pragma("unroll")                                             \
                for (int r = 0; r < 4; ++r)                                   \
                    _Pragma("unroll")                                         \
                    for (int t = 0; t < 2; ++t)                               \
                        acc1[r][(os) + t] = __builtin_amdgcn_mfma_f32_16x16x32_f16( \
                            Af[t], Bf[r + dy], acc1[r][(os) + t], 0, 0, 0);   \
            }                                                                 \
        }                                                                     \
    }

    // ---- conv1: 4 chunk phases ----
    PF_W(W1, 0, 32)  CONV1_CHUNK(0, 0) __syncthreads();
    WR_W()           __syncthreads();
    PF_W(W1, 32, 0)  CONV1_CHUNK(0, 2) __syncthreads();
    WR_W()           __syncthreads();
    PF_W(W1, 32, 32) CONV1_CHUNK(4, 0) __syncthreads();
    WR_W()           __syncthreads();
    PF_W(W2, 0, 0)   CONV1_CHUNK(4, 2)
    // capture residual granules to regs (sIn dies at next barrier)
    half4_t rs[3][4];
#pragma unroll
    for (int rr = 0; rr < 3; ++rr)
#pragma unroll
        for (int c = 0; c < 4; ++c) {
            int oc0 = c * 16 + lg * 4;
            int pl  = (m0 + rr + 2) * 17 + lx + 2;
            rs[rr][c] = *(const half4_t*)&sIn[pl * 64 + (((oc0 >> 3) ^ (pl & 7)) << 3) + (oc0 & 4)];
        }
    __syncthreads();

    // ---- P4: conv1 epilogue -> sMid (over sIn); write sW <- W2(ic0,oc0) ----
    {
        int gcol = bx * 13 + lx - 1;              // conv1-out col
        bool colok = (unsigned)gcol < (unsigned)WW;
#pragma unroll
        for (int r = 0; r < 4; ++r) {
            int o    = o0 + r;                    // conv1-out row -1..14
            int grow = by * 12 + o;
            bool ok  = colok && ((unsigned)grow < (unsigned)HH);
#pragma unroll
            for (int c = 0; c < 4; ++c) {
                int oc0 = c * 16 + lg * 4;
                f32x4 bv = *(const f32x4*)&b1[oc0];
                int pl2 = (o + 1) * 17 + lx;      // rows 0..15, cols 0..15
                half4_t ov;
#pragma unroll
                for (int q = 0; q < 4; ++q)
                    ov[q] = ok ? (_Float16)fmaxf(acc1[r][c][q] + bv[q], 0.f)
                               : (_Float16)0.f;
                *(half4_t*)&sMid[pl2 * 64 + (((oc0 >> 3) ^ (pl2 & 7)) << 3) + (oc0 & 4)] = ov;
            }
        }
    }
    WR_W()
    __syncthreads();

    f32x4 acc2[3][4];   // [row][ochalf*2 + t]
#pragma unroll
    for (int rr = 0; rr < 3; ++rr)
#pragma unroll
        for (int t = 0; t < 4; ++t) acc2[rr][t] = (f32x4){0.f, 0.f, 0.f, 0.f};

// conv2 compute: out rows m0..m0+2; B rows m0+d (d 0..4), all <= 13.
#define CONV2_CHUNK(ch, os)                                                   \
    {                                                                         \
        _Pragma("unroll")                                                     \
        for (int dx = 0; dx < 3; ++dx) {                                      \
            half8 Bf[5];                                                      \
            _Pragma("unroll")                                                 \
            for (int d = 0; d < 5; ++d) {                                     \
                int pl = (m0 + d) * 17 + (lx + dx);                           \
                Bf[d] = *(const half8*)&sMid[pl * 64 + ((((ch) + lg) ^ (pl & 7)) << 3)]; \
            }                                                                 \
            _Pragma("unroll")                                                 \
            for (int dy = 0; dy < 3; ++dy) {                                  \
                int tap = dy * 3 + dx;                                        \
                half8 Af[2];                                                  \
                _Pragma("unroll")                                             \
                for (int t = 0; t < 2; ++t) Af[t] = RD_A(tap, t * 16 + lx);   \
                _Pragma("unroll")                                             \
                for (int rr = 0; rr < 3; ++rr)                                \
                    _Pragma("unroll")                                         \
                    for (int t = 0; t < 2; ++t)                               \
                        acc2[rr][(os) + t] = __builtin_amdgcn_mfma_f32_16x16x32_f16( \
                            Af[t], Bf[rr + dy], acc2[rr][(os) + t], 0, 0, 0); \
            }                                                                 \
        }                                                                     \
    }

    // ---- conv2: 4 chunk phases ----
    PF_W(W2, 0, 32)  CONV2_CHUNK(0, 0) __syncthreads();
    WR_W()           __syncthreads();
    PF_W(W2, 32, 0)  CONV2_CHUNK(0, 2) __syncthreads();
    WR_W()           __syncthreads();
    PF_W(W2, 32, 32) CONV2_CHUNK(4, 0) __syncthreads();
    WR_W()           __syncthreads();
    CONV2_CHUNK(4, 2)
    // ---- final epilogue: bias + reg-residual, masked store ----
    {
        int gcol = bx * 13 + lx;
        bool sok = (lx < 13) && (gcol < WW);
#pragma unroll
        for (int rr = 0; rr < 3; ++rr) {
            int y = by * 12 + m0 + rr;
            if (!sok || y >= HH) continue;
#pragma unroll
            for (int c = 0; c < 4; ++c) {
                int oc0 = c * 16 + lg * 4;
                f32x4 bv = *(const f32x4*)&b2[oc0];
                size_t gi = ((((size_t)n * 16 + (oc0 >> 2)) * HH + y) * WW + gcol) * 4;
                half4_t ov;
#pragma unroll
                for (int q = 0; q < 4; ++q)
                    ov[q] = (_Float16)(acc2[rr][c][q] + bv[q] + (float)rs[rr][c][q]);
                *(half4_t*)&out[gi] = ov;
            }
        }
    }
#undef PF_W
#undef WR_W
#undef RD_A
#undef CONV1_CHUNK
#undef CONV2_CHUNK
}

// ---------------------------------------------------------------------------
// MFMA conv (r10-proven geometry): IC=64, 512 threads / 8 waves, tile 16x16.
// oc-loop chunks of 32 staged in LDS (xor, conflict-free). 16 waves/CU.
// ---------------------------------------------------------------------------
template<bool RES, bool NT>
__global__ __launch_bounds__(512, 2)
void mconv_k(const _Float16* __restrict__ in, const _Float16* __restrict__ Wt,
             const float* __restrict__ bias, const _Float16* __restrict__ resid,
             _Float16* __restrict__ out, int OCp, int OCr, int C4) {
    __shared__ __align__(16) _Float16 sIn[18 * 18 * 64];  // 41.5 KB
    __shared__ __align__(16) _Float16 sW[9 * 32 * 64];    // 36.9 KB

    int tid = threadIdx.x;
    int n = blockIdx.z, bx = blockIdx.x, by = blockIdx.y;

    for (int i = tid; i < 2592; i += 512) {
        int icg = i / 324, pl = i - icg * 324;
        int py = pl / 18, px = pl - py * 18;
        int gy = by * 16 + py - 1, gx = bx * 16 + px - 1;
        half8 v = {0, 0, 0, 0, 0, 0, 0, 0};
        if ((unsigned)gy < (unsigned)HH && (unsigned)gx < (unsigned)WW) {
            size_t base = ((((size_t)n * 16 + icg * 2) * HH + gy) * WW + gx) * 4;
            half4_t a = *(const half4_t*)&in[base];
            half4_t c = *(const half4_t*)&in[base + (size_t)HH * WW * 4];
            v[0] = a[0]; v[1] = a[1]; v[2] = a[2]; v[3] = a[3];
            v[4] = c[0]; v[5] = c[1]; v[6] = c[2]; v[7] = c[3];
        }
        *(half8*)&sIn[pl * 64 + ((icg ^ (pl & 7)) << 3)] = v;
    }
    __syncthreads();

    int wv = tid >> 6, lane = tid & 63;
    int lx = lane & 15, lg = lane >> 4;
    int r0 = wv * 2;
    int gx0 = bx * 16 + lx;

    for (int ocb = 0; ocb < OCp; ocb += 32) {
        __syncthreads();
        for (int i = tid; i < 2304; i += 512) {
            int tap = i >> 8, oc = (i >> 3) & 31, icg = i & 7;
            half8 v = *(const half8*)&Wt[((size_t)(tap * OCp + ocb + oc)) * 64 + icg * 8];
            *(half8*)&sW[(tap * 32 + oc) * 64 + ((icg ^ (oc & 7)) << 3)] = v;
        }
        __syncthreads();

        f32x4 acc[2][2];
#pragma unroll
        for (int r = 0; r < 2; ++r)
#pragma unroll
            for (int t = 0; t < 2; ++t) acc[r][t] = (f32x4){0.f, 0.f, 0.f, 0.f};

#pragma unroll
        for (int icstep = 0; icstep < 2; ++icstep) {
            int icg = icstep * 4 + lg;
#pragma unroll
            for (int dx = 0; dx < 3; ++dx) {
                half8 Bf[4];
#pragma unroll
                for (int d = 0; d < 4; ++d) {
                    int pl = (r0 + d) * 18 + lx + dx;
                    Bf[d] = *(const half8*)&sIn[pl * 64 + ((icg ^ (pl & 7)) << 3)];
                }
#pragma unroll
                for (int dy = 0; dy < 3; ++dy) {
                    int tap = dy * 3 + dx;
                    half8 Af[2];
#pragma unroll
                    for (int t = 0; t < 2; ++t) {
                        int oc = t * 16 + lx;
                        Af[t] = *(const half8*)&sW[(tap * 32 + oc) * 64 + ((icg ^ (oc & 7)) << 3)];
                    }
#pragma unroll
                    for (int r = 0; r < 2; ++r)
#pragma unroll
                        for (int t = 0; t < 2; ++t)
                            acc[r][t] = __builtin_amdgcn_mfma_f32_16x16x32_f16(
                                Af[t], Bf[r + dy], acc[r][t], 0, 0, 0);
                }
            }
        }
#pragma unroll
        for (int r = 0; r < 2; ++r) {
            int y = by * 16 + r0 + r;
#pragma unroll
            for (int t = 0; t < 2; ++t) {
                int oc0 = ocb + t * 16 + lg * 4;
                if (oc0 >= OCr) continue;
                f32x4 bv = *(const f32x4*)&bias[oc0];
                size_t gi = ((((size_t)n * C4 + (oc0 >> 2)) * HH + y) * WW + gx0) * 4;
                float vv[4];
#pragma unroll
                for (int q = 0; q < 4; ++q) vv[q] = acc[r][t][q] + bv[q];
                if (RES) {
                    half4_t rg = *(const half4_t*)&resid[gi];
#pragma unroll
                    for (int q = 0; q < 4; ++q) vv[q] += (float)rg[q];
                }
                half4_t o;
#pragma unroll
                for (int q = 0; q < 4; ++q) o[q] = (_Float16)vv[q];
                if (NT) __builtin_nontemporal_store(o, (half4_t*)&out[gi]);
                else    *(half4_t*)&out[gi] = o;
            }
        }
    }
}

// ---------------------------------------------------------------------------
// Out conv 100->3 over pixel-shuffled super output: ic-PAIR interleaved LDS
// staging + v_dot2_f32_f16 (no converts; weights pre-packed as half2).
// ---------------------------------------------------------------------------
__global__ __launch_bounds__(256)
void out_k(const _Float16* __restrict__ S, const _Float16* __restrict__ Wo,
           const float* __restrict__ b, float* __restrict__ out) {
    __shared__ __align__(16) _Float16 sG[5 * 324 * 8];  // 25.9 KB
    int n = blockIdx.z;
    int tid = threadIdx.x;
    int ty = tid >> 4, tx = tid & 15;
    int a  = blockIdx.y * 16 + ty;
    int bc = blockIdx.x * 16 + tx;
    float acc[3][2][2];
#pragma unroll
    for (int c = 0; c < 3; ++c)
#pragma unroll
        for (int oy = 0; oy < 2; ++oy)
#pragma unroll
            for (int ox = 0; ox < 2; ++ox) acc[c][oy][ox] = 0.f;

    for (int ch = 0; ch < 10; ++ch) {
        __syncthreads();
        for (int i = tid; i < 1620; i += 256) {
            int p = i / 324, pl = i - p * 324;
            int py = pl / 18, px = pl - py * 18;
            int Y = blockIdx.y * 16 + py - 1, X = blockIdx.x * 16 + px - 1;
            half4_t va = {0, 0, 0, 0}, vc = {0, 0, 0, 0};
            if ((unsigned)Y < 128u && (unsigned)X < 128u) {
                size_t base = ((((size_t)n * 100 + ch * 10 + p * 2) * 128 + Y) * 128 + X) * 4;
                va = *(const half4_t*)&S[base];
                vc = *(const half4_t*)&S[base + (size_t)128 * 128 * 4];
            }
            half8 v;
            v[0] = va[0]; v[1] = vc[0]; v[2] = va[1]; v[3] = vc[1];
            v[4] = va[2]; v[5] = vc[2]; v[6] = va[3]; v[7] = vc[3];
            *(half8*)&sG[(p * 324 + pl) * 8] = v;
        }
        __syncthreads();
#pragma unroll
        for (int p = 0; p < 5; ++p) {
            half2_t wv[3][9];
#pragma unroll
            for (int c = 0; c < 3; ++c)
#pragma unroll
                for (int t = 0; t < 9; ++t)
                    wv[c][t] = *(const half2_t*)&Wo[((c * 50 + ch * 5 + p) * 9 + t) * 2];
            half8 G[3][3];
#pragma unroll
            for (int yi = 0; yi < 3; ++yi)
#pragma unroll
                for (int xi = 0; xi < 3; ++xi)
                    G[yi][xi] = *(const half8*)&sG[(p * 324 + (ty + yi) * 18 + tx + xi) * 8];
#pragma unroll
            for (int oy = 0; oy < 2; ++oy)
#pragma unroll
                for (int ox = 0; ox < 2; ++ox)
#pragma unroll
                    for (int dy = 0; dy < 3; ++dy)
#pragma unroll
                        for (int dx = 0; dx < 3; ++dx) {
                            const int ey = oy + dy - 1, ex = ox + dx - 1;
                            const int yi = (ey >> 1) + 1, xi = (ex >> 1) + 1;
                            const int sub = (ey & 1) * 2 + (ex & 1);
                            half8 g8 = G[yi][xi];
                            half2_t gp = {g8[2 * sub], g8[2 * sub + 1]};
#pragma unroll
                            for (int c = 0; c < 3; ++c)
                                acc[c][oy][ox] = __builtin_amdgcn_fdot2(
                                    gp, wv[c][dy * 3 + dx], acc[c][oy][ox], false);
                        }
        }
    }
    const float madd[3] = {255.0f * 0.4488f, 255.0f * 0.4371f, 255.0f * 0.4040f};
#pragma unroll
    for (int c = 0; c < 3; ++c)
#pragma unroll
        for (int oy = 0; oy < 2; ++oy)
#pragma unroll
            for (int ox = 0; ox < 2; ++ox)
                out[(((size_t)n * 3 + c) * 256 + 2 * a + oy) * 256 + 2 * bc + ox] =
                    acc[c][oy][ox] + b[c] + madd[c];
}

// ---------------------------------------------------------------------------
extern "C" void kernel_launch(void* const* d_in, const int* in_sizes, int n_in,
                              void* d_out, int out_size, void* d_ws, size_t ws_size,
                              hipStream_t stream) {
    const float* x       = (const float*)d_in[0];
    const float* head_w  = (const float*)d_in[1];
    const float* head_b  = (const float*)d_in[2];
    const float* rb_w1   = (const float*)d_in[3];
    const float* rb_b1   = (const float*)d_in[4];
    const float* rb_w2   = (const float*)d_in[5];
    const float* rb_b2   = (const float*)d_in[6];
    const float* body_w  = (const float*)d_in[7];
    const float* body_b  = (const float*)d_in[8];
    const float* super_w = (const float*)d_in[9];
    const float* super_b = (const float*)d_in[10];
    const float* out_w   = (const float*)d_in[11];
    const float* out_b   = (const float*)d_in[12];
    float* out = (float*)d_out;

    const size_t ACT = (size_t)16777216;  // bytes per f16 activation buffer
    char* wsb = (char*)d_ws;
    _Float16* Tb = (_Float16*)wsb;                      // ping / body-out / super-in
    _Float16* Hb = (_Float16*)(wsb + ACT);              // head out (kept for body skip)
    _Float16* Cb = (_Float16*)(wsb + 2 * ACT);          // pong
    _Float16* Sb = (_Float16*)(wsb + ACT);              // super out (Hb/Cb dead then)
    _Float16* Wt = (_Float16*)(wsb + ACT + 104857600);  // 1474560 f16
    _Float16* Wo = (_Float16*)(wsb + ACT + 104857600 + 2949120);  // 2700 f16

    // 0) weight transform
    wxform_k<<<dim3(1440), 256, 0, stream>>>(rb_w1, rb_w2, body_w, super_w,
                                             out_w, Wt, Wo);

    // 1) head
    head_k<<<dim3(8, 8, 8), 256, 0, stream>>>(x, head_w, head_b, Hb);

    const _Float16* Wt_bod = Wt + (size_t)32 * 36864;
    const _Float16* Wt_sup = Wt + (size_t)33 * 36864;

    // 2) fused resblocks, one launch per layer (ping-pong Tb/Cb; Hb preserved)
    const _Float16* cur = Hb;
    for (int i = 0; i < 16; ++i) {
        _Float16* dst = (i & 1) ? Cb : Tb;
        frb1_k<<<dim3(10, 11, 8), 256, 0, stream>>>(
            cur, Wt + (size_t)i * 36864, Wt + (size_t)(16 + i) * 36864,
            rb_b1 + i * 64, rb_b2 + i * 64, dst);
        cur = dst;
    }
    // chain output = Cb
    // 3) body conv + head skip -> Tb
    mconv_k<true, false><<<dim3(8, 8, 8), 512, 0, stream>>>(
        Cb, Wt_bod, body_b, Hb, Tb, 64, 64, 16);
    // 4) super conv 64->400 (padded 448) -> Sb, nontemporal stores
    mconv_k<false, true><<<dim3(8, 8, 8), 512, 0, stream>>>(
        Tb, Wt_sup, super_b, nullptr, Sb, 448, 400, 100);
    // 5) out conv (dot2) over pixel-shuffled pair-granules + mean add
    out_k<<<dim3(8, 8, 8), 256, 0, stream>>>(Sb, Wo, out_b, out);
}

// Round 13
// 874.047 us; speedup vs baseline: 1.4810x; 1.4810x over previous
//
#include <hip/hip_runtime.h>
#include <hip/hip_bf16.h>

#define HH 128
#define WW 128

typedef _Float16 half2_t __attribute__((ext_vector_type(2)));
typedef _Float16 half4_t __attribute__((ext_vector_type(4)));
typedef _Float16 half8 __attribute__((ext_vector_type(8)));
typedef float f32x4 __attribute__((ext_vector_type(4)));

// ---------------------------------------------------------------------------
// Weight transform: fp32 [oc][ic][3][3] -> f16 [tap][oc][ic] per layer.
// Layers 0..15 rb_w1, 16..31 rb_w2, 32 body (OC=64), 33 super (OC padded 448).
// Plus out-conv weights packed as f16 ic-PAIRS: Wo[(c*50+p)*9+tap] = half2.
// ---------------------------------------------------------------------------
__global__ __launch_bounds__(256)
void wxform_k(const float* __restrict__ rb_w1, const float* __restrict__ rb_w2,
              const float* __restrict__ body_w, const float* __restrict__ super_w,
              const float* __restrict__ out_w,
              _Float16* __restrict__ Wt, _Float16* __restrict__ Wo) {
    const int per64 = 64 * 64 * 9;          // 36864
    const int n64   = 33 * per64;           // 1216512
    const int nW    = n64 + 448 * 64 * 9;   // 1474560
    const int total = nW + 1350;            // + out-conv pairs
    for (int i = blockIdx.x * 256 + threadIdx.x; i < total; i += gridDim.x * 256) {
        if (i < n64) {
            int l  = i / per64;
            int r  = i - l * per64;
            int ic = r & 63, oc = (r >> 6) & 63, tap = r >> 12;
            const float* src = (l < 16) ? (rb_w1 + (size_t)l * per64)
                             : (l < 32) ? (rb_w2 + (size_t)(l - 16) * per64)
                                        : body_w;
            Wt[i] = (_Float16)src[(oc * 64 + ic) * 9 + tap];
        } else if (i < nW) {
            int r   = i - n64;
            int ic  = r & 63;
            int oc  = (r >> 6) % 448;
            int tap = (r >> 6) / 448;
            float v = (oc < 400) ? super_w[((size_t)oc * 64 + ic) * 9 + tap] : 0.f;
            Wt[i] = (_Float16)v;
        } else {
            int j = i - nW;            // 0..1349 : c(3) x p(50) x tap(9)
            int c = j / 450, r = j - c * 450;
            int p = r / 9, tap = r - p * 9;
            Wo[j * 2]     = (_Float16)out_w[(c * 100 + 2 * p) * 9 + tap];
            Wo[j * 2 + 1] = (_Float16)out_w[(c * 100 + 2 * p + 1) * 9 + tap];
        }
    }
}

// ---------------------------------------------------------------------------
// Head conv: 3 -> 64, fused mean subtraction. Output f16 4c layout.
// ---------------------------------------------------------------------------
__global__ __launch_bounds__(256)
void head_k(const float* __restrict__ x, const float* __restrict__ w,
            const float* __restrict__ b, _Float16* __restrict__ out) {
    int n  = blockIdx.z;
    int gx = blockIdx.x * 16 + (threadIdx.x & 15);
    int gy = blockIdx.y * 16 + (threadIdx.x >> 4);
    float msub[3] = {255.0f * 0.4488f, 255.0f * 0.4371f, 255.0f * 0.4040f};
    float iv[27];
#pragma unroll
    for (int c = 0; c < 3; ++c)
#pragma unroll
        for (int dy = 0; dy < 3; ++dy)
#pragma unroll
            for (int dx = 0; dx < 3; ++dx) {
                int yy = gy + dy - 1, xx = gx + dx - 1;
                float v = 0.f;
                if ((unsigned)yy < HH && (unsigned)xx < WW)
                    v = x[(((size_t)n * 3 + c) * HH + yy) * WW + xx] - msub[c];
                iv[c * 9 + dy * 3 + dx] = v;
            }
    for (int ocg = 0; ocg < 16; ++ocg) {
        half4_t o;
#pragma unroll
        for (int q = 0; q < 4; ++q) {
            int oc  = ocg * 4 + q;
            float a = b[oc];
#pragma unroll
            for (int t = 0; t < 27; ++t) a = fmaf(iv[t], w[oc * 27 + t], a);
            o[q] = (_Float16)a;
        }
        *(half4_t*)&out[((((size_t)n * 16 + ocg) * HH + gy) * WW + gx) * 4] = o;
    }
}

// ---------------------------------------------------------------------------
// Fused resblock (r11-proven, best measured ~42 us/layer): 14x12 output tile,
// conv1-out 16 cols x 16 rows (exact lane width, no duplicated columns).
// conv1: 4 waves x 4 rows. conv2: 2 row-groups(6) x 2 oc-halves.
// sIn 16x18x64 aliased by sMid; sW oc-pair-packed 64-wide rows (<=2-way
// banks). LDS 73.7 KB -> 2 blocks/CU. 8 barriers. Reg-prefetch of weights.
// ---------------------------------------------------------------------------
__global__ __launch_bounds__(256, 2)
void frb1_k(const _Float16* __restrict__ in, const _Float16* __restrict__ W1,
            const _Float16* __restrict__ W2, const float* __restrict__ b1,
            const float* __restrict__ b2, _Float16* __restrict__ out) {
    __shared__ __align__(16) _Float16 sBuf[18432 + 18432];  // 73.7 KB
    _Float16* sIn  = sBuf;          // 16 rows x 18 cols x 64 ic (staging+conv1)
    _Float16* sMid = sBuf;          // 16 rows x 18 cols x 64 oc (aliased)
    _Float16* sW   = sBuf + 18432;  // 9 tap x 32 oc-pairs x 64 (one ic-half)

    int tid = threadIdx.x;
    int bx = blockIdx.x, by = blockIdx.y, n = blockIdx.z;
    int wv = tid >> 6, lane = tid & 63;
    int lx = lane & 15, lg = lane >> 4;
    int o0 = wv * 4 - 1;            // conv1-out rows o0..o0+3 (covers -1..14)
    int g2 = wv & 1;                // conv2 row-group (rows g2*6 .. +5)
    int hh = wv >> 1;               // conv2 oc-half

    half8 pf[9];
#define PF_W(Wsrc, h)                                                         \
    _Pragma("unroll")                                                         \
    for (int j = 0; j < 9; ++j) {                                             \
        int i = tid + 256 * j;                                                \
        int g = i & 3, oc = (i >> 2) & 63, tap = i >> 8;                      \
        pf[j] = *(const half8*)&Wsrc[(size_t)(tap * 64 + oc) * 64 + (h) * 32 + g * 8]; \
    }
#define WR_W()                                                                \
    _Pragma("unroll")                                                         \
    for (int j = 0; j < 9; ++j) {                                             \
        int i = tid + 256 * j;                                                \
        int g = i & 3, oc = (i >> 2) & 63, tap = i >> 8;                      \
        *(half8*)&sW[(tap * 32 + (oc >> 1)) * 64 +                            \
                     (((g + (oc & 1) * 4) ^ ((oc >> 1) & 7)) << 3)] = pf[j];  \
    }
#define RD_A(tap, oc)                                                         \
    (*(const half8*)&sW[((tap) * 32 + ((oc) >> 1)) * 64 +                     \
                        (((lg + ((oc) & 1) * 4) ^ (((oc) >> 1) & 7)) << 3)])

    // ---- P0: prefetch W1h0, stage sIn (16x18), write sW ----
    PF_W(W1, 0)
    for (int i = tid; i < 2304; i += 256) {
        int icg = i / 288, pl = i - icg * 288;
        int py = pl / 18, px = pl - py * 18;
        int gy = by * 12 + py - 2, gx = bx * 14 + px - 2;
        half8 v = {0, 0, 0, 0, 0, 0, 0, 0};
        if ((unsigned)gy < (unsigned)HH && (unsigned)gx < (unsigned)WW) {
            size_t base = ((((size_t)n * 16 + icg * 2) * HH + gy) * WW + gx) * 4;
            half4_t a = *(const half4_t*)&in[base];
            half4_t c = *(const half4_t*)&in[base + (size_t)HH * WW * 4];
            v[0] = a[0]; v[1] = a[1]; v[2] = a[2]; v[3] = a[3];
            v[4] = c[0]; v[5] = c[1]; v[6] = c[2]; v[7] = c[3];
        }
        *(half8*)&sIn[pl * 64 + ((icg ^ (pl & 7)) << 3)] = v;
    }
    WR_W()
    __syncthreads();

    f32x4 acc1[4][4];
#pragma unroll
    for (int r = 0; r < 4; ++r)
#pragma unroll
        for (int t = 0; t < 4; ++t) acc1[r][t] = (f32x4){0.f, 0.f, 0.f, 0.f};

#define CONV1_CHUNK(h)                                                        \
    {                                                                         \
        _Pragma("unroll")                                                     \
        for (int dx = 0; dx < 3; ++dx) {                                      \
            half8 Bf[6];                                                      \
            _Pragma("unroll")                                                 \
            for (int d = 0; d < 6; ++d) {                                     \
                int pl = (o0 + d + 1) * 18 + (lx + dx);                       \
                Bf[d] = *(const half8*)&sIn[pl * 64 + ((((h) * 4 + lg) ^ (pl & 7)) << 3)]; \
            }                                                                 \
            _Pragma("unroll")                                                 \
            for (int dy = 0; dy < 3; ++dy) {                                  \
                int tap = dy * 3 + dx;                                        \
                half8 Af[4];                                                  \
                _Pragma("unroll")                                             \
                for (int t = 0; t < 4; ++t) Af[t] = RD_A(tap, t * 16 + lx);   \
                _Pragma("unroll")                                             \
                for (int r = 0; r < 4; ++r)                                   \
                    _Pragma("unroll")                                         \
                    for (int t = 0; t < 4; ++t)                               \
                        acc1[r][t] = __builtin_amdgcn_mfma_f32_16x16x32_f16(  \
                            Af[t], Bf[r + dy], acc1[r][t], 0, 0, 0);          \
            }                                                                 \
        }                                                                     \
    }

    // ---- P1: prefetch W1h1; conv1 ic-half 0 ----
    PF_W(W1, 1)
    CONV1_CHUNK(0)
    __syncthreads();
    // ---- P2: write sW <- W1h1 ----
    WR_W()
    __syncthreads();
    // ---- P3: prefetch W2h0; conv1 ic-half 1; capture residual to regs ----
    PF_W(W2, 0)
    CONV1_CHUNK(1)
    half4_t rs[6][2];
#pragma unroll
    for (int r = 0; r < 6; ++r)
#pragma unroll
        for (int t = 0; t < 2; ++t) {
            int oc0 = hh * 32 + t * 16 + lg * 4;
            int pl  = (g2 * 6 + r + 2) * 18 + lx + 2;
            rs[r][t] = *(const half4_t*)&sIn[pl * 64 + (((oc0 >> 3) ^ (pl & 7)) << 3) + (oc0 & 4)];
        }
    __syncthreads();

    // ---- P4: conv1 epilogue -> sMid (over sIn); write sW <- W2h0 ----
    {
        int gcol = bx * 14 + lx - 1;
        bool colok = (unsigned)gcol < (unsigned)WW;
#pragma unroll
        for (int r = 0; r < 4; ++r) {
            int o    = o0 + r;                        // conv1-out row -1..14
            int grow = by * 12 + o;
            bool ok  = colok && ((unsigned)grow < (unsigned)HH);
#pragma unroll
            for (int t = 0; t < 4; ++t) {
                int oc0 = t * 16 + lg * 4;
                f32x4 bv = *(const f32x4*)&b1[oc0];
                int pl2 = (o + 1) * 18 + lx;          // sMid row 0..15, col 0..15
                half4_t ov;
#pragma unroll
                for (int q = 0; q < 4; ++q)
                    ov[q] = ok ? (_Float16)fmaxf(acc1[r][t][q] + bv[q], 0.f)
                               : (_Float16)0.f;
                *(half4_t*)&sMid[pl2 * 64 + (((oc0 >> 3) ^ (pl2 & 7)) << 3) + (oc0 & 4)] = ov;
            }
        }
    }
    WR_W()
    __syncthreads();

    f32x4 acc2[6][2];
#pragma unroll
    for (int r = 0; r < 6; ++r)
#pragma unroll
        for (int t = 0; t < 2; ++t) acc2[r][t] = (f32x4){0.f, 0.f, 0.f, 0.f};

#define CONV2_CHUNK(h)                                                        \
    {                                                                         \
        _Pragma("unroll")                                                     \
        for (int dx = 0; dx < 3; ++dx) {                                      \
            half8 Bf[8];                                                      \
            _Pragma("unroll")                                                 \
            for (int d = 0; d < 8; ++d) {                                     \
                int pl = (g2 * 6 + d) * 18 + (lx + dx);                       \
                Bf[d] = *(const half8*)&sMid[pl * 64 + ((((h) * 4 + lg) ^ (pl & 7)) << 3)]; \
            }                                                                 \
            _Pragma("unroll")                                                 \
            for (int dy = 0; dy < 3; ++dy) {                                  \
                int tap = dy * 3 + dx;                                        \
                half8 Af[2];                                                  \
                _Pragma("unroll")                                             \
                for (int t = 0; t < 2; ++t) Af[t] = RD_A(tap, hh * 32 + t * 16 + lx); \
                _Pragma("unroll")                                             \
                for (int r = 0; r < 6; ++r)                                   \
                    _Pragma("unroll")                                         \
                    for (int t = 0; t < 2; ++t)                               \
                        acc2[r][t] = __builtin_amdgcn_mfma_f32_16x16x32_f16(  \
                            Af[t], Bf[r + dy], acc2[r][t], 0, 0, 0);          \
            }                                                                 \
        }                                                                     \
    }

    // ---- P5: prefetch W2h1; conv2 ic-half 0 ----
    PF_W(W2, 1)
    CONV2_CHUNK(0)
    __syncthreads();
    // ---- P6: write sW <- W2h1 ----
    WR_W()
    __syncthreads();
    // ---- P7: conv2 ic-half 1 + epilogue (bias + reg-residual) ----
    CONV2_CHUNK(1)
    {
        int gcol = bx * 14 + lx;
        bool sok = (lx < 14) && (gcol < WW);
#pragma unroll
        for (int r = 0; r < 6; ++r) {
            int y = by * 12 + g2 * 6 + r;
            if (!sok || y >= HH) continue;
#pragma unroll
            for (int t = 0; t < 2; ++t) {
                int oc0 = hh * 32 + t * 16 + lg * 4;
                f32x4 bv = *(const f32x4*)&b2[oc0];
                size_t gi = ((((size_t)n * 16 + (oc0 >> 2)) * HH + y) * WW + gcol) * 4;
                half4_t ov;
#pragma unroll
                for (int q = 0; q < 4; ++q)
                    ov[q] = (_Float16)(acc2[r][t][q] + bv[q] + (float)rs[r][t][q]);
                *(half4_t*)&out[gi] = ov;
            }
        }
    }
#undef PF_W
#undef WR_W
#undef RD_A
#undef CONV1_CHUNK
#undef CONV2_CHUNK
}

// ---------------------------------------------------------------------------
// MFMA conv (r10-proven geometry, best measured super 74.5 us): IC=64,
// 512 threads / 8 waves, tile 16x16 px, waves = 8 row-groups of 2 rows.
// oc-loop chunks of 32 staged in LDS (xor, conflict-free). 16 waves/CU.
// ---------------------------------------------------------------------------
template<bool RES, bool NT>
__global__ __launch_bounds__(512, 2)
void mconv_k(const _Float16* __restrict__ in, const _Float16* __restrict__ Wt,
             const float* __restrict__ bias, const _Float16* __restrict__ resid,
             _Float16* __restrict__ out, int OCp, int OCr, int C4) {
    __shared__ __align__(16) _Float16 sIn[18 * 18 * 64];  // 41.5 KB
    __shared__ __align__(16) _Float16 sW[9 * 32 * 64];    // 36.9 KB

    int tid = threadIdx.x;
    int n = blockIdx.z, bx = blockIdx.x, by = blockIdx.y;

    for (int i = tid; i < 2592; i += 512) {
        int icg = i / 324, pl = i - icg * 324;
        int py = pl / 18, px = pl - py * 18;
        int gy = by * 16 + py - 1, gx = bx * 16 + px - 1;
        half8 v = {0, 0, 0, 0, 0, 0, 0, 0};
        if ((unsigned)gy < (unsigned)HH && (unsigned)gx < (unsigned)WW) {
            size_t base = ((((size_t)n * 16 + icg * 2) * HH + gy) * WW + gx) * 4;
            half4_t a = *(const half4_t*)&in[base];
            half4_t c = *(const half4_t*)&in[base + (size_t)HH * WW * 4];
            v[0] = a[0]; v[1] = a[1]; v[2] = a[2]; v[3] = a[3];
            v[4] = c[0]; v[5] = c[1]; v[6] = c[2]; v[7] = c[3];
        }
        *(half8*)&sIn[pl * 64 + ((icg ^ (pl & 7)) << 3)] = v;
    }
    __syncthreads();

    int wv = tid >> 6, lane = tid & 63;
    int lx = lane & 15, lg = lane >> 4;
    int r0 = wv * 2;
    int gx0 = bx * 16 + lx;

    for (int ocb = 0; ocb < OCp; ocb += 32) {
        __syncthreads();
        for (int i = tid; i < 2304; i += 512) {
            int tap = i >> 8, oc = (i >> 3) & 31, icg = i & 7;
            half8 v = *(const half8*)&Wt[((size_t)(tap * OCp + ocb + oc)) * 64 + icg * 8];
            *(half8*)&sW[(tap * 32 + oc) * 64 + ((icg ^ (oc & 7)) << 3)] = v;
        }
        __syncthreads();

        f32x4 acc[2][2];
#pragma unroll
        for (int r = 0; r < 2; ++r)
#pragma unroll
            for (int t = 0; t < 2; ++t) acc[r][t] = (f32x4){0.f, 0.f, 0.f, 0.f};

#pragma unroll
        for (int icstep = 0; icstep < 2; ++icstep) {
            int icg = icstep * 4 + lg;
#pragma unroll
            for (int dx = 0; dx < 3; ++dx) {
                half8 Bf[4];
#pragma unroll
                for (int d = 0; d < 4; ++d) {
                    int pl = (r0 + d) * 18 + lx + dx;
                    Bf[d] = *(const half8*)&sIn[pl * 64 + ((icg ^ (pl & 7)) << 3)];
                }
#pragma unroll
                for (int dy = 0; dy < 3; ++dy) {
                    int tap = dy * 3 + dx;
                    half8 Af[2];
#pragma unroll
                    for (int t = 0; t < 2; ++t) {
                        int oc = t * 16 + lx;
                        Af[t] = *(const half8*)&sW[(tap * 32 + oc) * 64 + ((icg ^ (oc & 7)) << 3)];
                    }
#pragma unroll
                    for (int r = 0; r < 2; ++r)
#pragma unroll
                        for (int t = 0; t < 2; ++t)
                            acc[r][t] = __builtin_amdgcn_mfma_f32_16x16x32_f16(
                                Af[t], Bf[r + dy], acc[r][t], 0, 0, 0);
                }
            }
        }
#pragma unroll
        for (int r = 0; r < 2; ++r) {
            int y = by * 16 + r0 + r;
#pragma unroll
            for (int t = 0; t < 2; ++t) {
                int oc0 = ocb + t * 16 + lg * 4;
                if (oc0 >= OCr) continue;
                f32x4 bv = *(const f32x4*)&bias[oc0];
                size_t gi = ((((size_t)n * C4 + (oc0 >> 2)) * HH + y) * WW + gx0) * 4;
                float vv[4];
#pragma unroll
                for (int q = 0; q < 4; ++q) vv[q] = acc[r][t][q] + bv[q];
                if (RES) {
                    half4_t rg = *(const half4_t*)&resid[gi];
#pragma unroll
                    for (int q = 0; q < 4; ++q) vv[q] += (float)rg[q];
                }
                half4_t o;
#pragma unroll
                for (int q = 0; q < 4; ++q) o[q] = (_Float16)vv[q];
                if (NT) __builtin_nontemporal_store(o, (half4_t*)&out[gi]);
                else    *(half4_t*)&out[gi] = o;
            }
        }
    }
}

// ---------------------------------------------------------------------------
// Out conv 100->3 over pixel-shuffled super output: ic-PAIR interleaved LDS
// staging + v_dot2_f32_f16 (no converts; weights pre-packed as half2).
// ---------------------------------------------------------------------------
__global__ __launch_bounds__(256)
void out_k(const _Float16* __restrict__ S, const _Float16* __restrict__ Wo,
           const float* __restrict__ b, float* __restrict__ out) {
    __shared__ __align__(16) _Float16 sG[5 * 324 * 8];  // 25.9 KB
    int n = blockIdx.z;
    int tid = threadIdx.x;
    int ty = tid >> 4, tx = tid & 15;
    int a  = blockIdx.y * 16 + ty;
    int bc = blockIdx.x * 16 + tx;
    float acc[3][2][2];
#pragma unroll
    for (int c = 0; c < 3; ++c)
#pragma unroll
        for (int oy = 0; oy < 2; ++oy)
#pragma unroll
            for (int ox = 0; ox < 2; ++ox) acc[c][oy][ox] = 0.f;

    for (int ch = 0; ch < 10; ++ch) {
        __syncthreads();
        for (int i = tid; i < 1620; i += 256) {
            int p = i / 324, pl = i - p * 324;
            int py = pl / 18, px = pl - py * 18;
            int Y = blockIdx.y * 16 + py - 1, X = blockIdx.x * 16 + px - 1;
            half4_t va = {0, 0, 0, 0}, vc = {0, 0, 0, 0};
            if ((unsigned)Y < 128u && (unsigned)X < 128u) {
                size_t base = ((((size_t)n * 100 + ch * 10 + p * 2) * 128 + Y) * 128 + X) * 4;
                va = *(const half4_t*)&S[base];
                vc = *(const half4_t*)&S[base + (size_t)128 * 128 * 4];
            }
            half8 v;
            v[0] = va[0]; v[1] = vc[0]; v[2] = va[1]; v[3] = vc[1];
            v[4] = va[2]; v[5] = vc[2]; v[6] = va[3]; v[7] = vc[3];
            *(half8*)&sG[(p * 324 + pl) * 8] = v;
        }
        __syncthreads();
#pragma unroll
        for (int p = 0; p < 5; ++p) {
            half2_t wv[3][9];
#pragma unroll
            for (int c = 0; c < 3; ++c)
#pragma unroll
                for (int t = 0; t < 9; ++t)
                    wv[c][t] = *(const half2_t*)&Wo[((c * 50 + ch * 5 + p) * 9 + t) * 2];
            half8 G[3][3];
#pragma unroll
            for (int yi = 0; yi < 3; ++yi)
#pragma unroll
                for (int xi = 0; xi < 3; ++xi)
                    G[yi][xi] = *(const half8*)&sG[(p * 324 + (ty + yi) * 18 + tx + xi) * 8];
#pragma unroll
            for (int oy = 0; oy < 2; ++oy)
#pragma unroll
                for (int ox = 0; ox < 2; ++ox)
#pragma unroll
                    for (int dy = 0; dy < 3; ++dy)
#pragma unroll
                        for (int dx = 0; dx < 3; ++dx) {
                            const int ey = oy + dy - 1, ex = ox + dx - 1;
                            const int yi = (ey >> 1) + 1, xi = (ex >> 1) + 1;
                            const int sub = (ey & 1) * 2 + (ex & 1);
                            half8 g8 = G[yi][xi];
                            half2_t gp = {g8[2 * sub], g8[2 * sub + 1]};
#pragma unroll
                            for (int c = 0; c < 3; ++c)
                                acc[c][oy][ox] = __builtin_amdgcn_fdot2(
                                    gp, wv[c][dy * 3 + dx], acc[c][oy][ox], false);
                        }
        }
    }
    const float madd[3] = {255.0f * 0.4488f, 255.0f * 0.4371f, 255.0f * 0.4040f};
#pragma unroll
    for (int c = 0; c < 3; ++c)
#pragma unroll
        for (int oy = 0; oy < 2; ++oy)
#pragma unroll
            for (int ox = 0; ox < 2; ++ox)
                out[(((size_t)n * 3 + c) * 256 + 2 * a + oy) * 256 + 2 * bc + ox] =
                    acc[c][oy][ox] + b[c] + madd[c];
}

// ---------------------------------------------------------------------------
extern "C" void kernel_launch(void* const* d_in, const int* in_sizes, int n_in,
                              void* d_out, int out_size, void* d_ws, size_t ws_size,
                              hipStream_t stream) {
    const float* x       = (const float*)d_in[0];
    const float* head_w  = (const float*)d_in[1];
    const float* head_b  = (const float*)d_in[2];
    const float* rb_w1   = (const float*)d_in[3];
    const float* rb_b1   = (const float*)d_in[4];
    const float* rb_w2   = (const float*)d_in[5];
    const float* rb_b2   = (const float*)d_in[6];
    const float* body_w  = (const float*)d_in[7];
    const float* body_b  = (const float*)d_in[8];
    const float* super_w = (const float*)d_in[9];
    const float* super_b = (const float*)d_in[10];
    const float* out_w   = (const float*)d_in[11];
    const float* out_b   = (const float*)d_in[12];
    float* out = (float*)d_out;

    const size_t ACT = (size_t)16777216;  // bytes per f16 activation buffer
    char* wsb = (char*)d_ws;
    _Float16* Tb = (_Float16*)wsb;                      // ping / body-out / super-in
    _Float16* Hb = (_Float16*)(wsb + ACT);              // head out (kept for body skip)
    _Float16* Cb = (_Float16*)(wsb + 2 * ACT);          // pong
    _Float16* Sb = (_Float16*)(wsb + ACT);              // super out (Hb/Cb dead then)
    _Float16* Wt = (_Float16*)(wsb + ACT + 104857600);  // 1474560 f16
    _Float16* Wo = (_Float16*)(wsb + ACT + 104857600 + 2949120);  // 2700 f16

    // 0) weight transform
    wxform_k<<<dim3(1440), 256, 0, stream>>>(rb_w1, rb_w2, body_w, super_w,
                                             out_w, Wt, Wo);

    // 1) head
    head_k<<<dim3(8, 8, 8), 256, 0, stream>>>(x, head_w, head_b, Hb);

    const _Float16* Wt_bod = Wt + (size_t)32 * 36864;
    const _Float16* Wt_sup = Wt + (size_t)33 * 36864;

    // 2) fused resblocks, one launch per layer (ping-pong Tb/Cb; Hb preserved)
    const _Float16* cur = Hb;
    for (int i = 0; i < 16; ++i) {
        _Float16* dst = (i & 1) ? Cb : Tb;
        frb1_k<<<dim3(10, 11, 8), 256, 0, stream>>>(
            cur, Wt + (size_t)i * 36864, Wt + (size_t)(16 + i) * 36864,
            rb_b1 + i * 64, rb_b2 + i * 64, dst);
        cur = dst;
    }
    // chain output = Cb
    // 3) body conv + head skip -> Tb
    mconv_k<true, false><<<dim3(8, 8, 8), 512, 0, stream>>>(
        Cb, Wt_bod, body_b, Hb, Tb, 64, 64, 16);
    // 4) super conv 64->400 (padded 448) -> Sb, nontemporal stores
    mconv_k<false, true><<<dim3(8, 8, 8), 512, 0, stream>>>(
        Tb, Wt_sup, super_b, nullptr, Sb, 448, 400, 100);
    // 5) out conv (dot2) over pixel-shuffled pair-granules + mean add
    out_k<<<dim3(8, 8, 8), 256, 0, stream>>>(Sb, Wo, out_b, out);
}